// Round 5
// baseline (742.968 us; speedup 1.0000x reference)
//
#include <hip/hip_runtime.h>

#define H 192
#define W 192
#define HW (192 * 192)

// LDS-staged window geometry: tile 32x16, halo 21 (+1 bilinear corner)
#define TX 32
#define TY 16
#define HALO 21
#define WC (TX + 2 * HALO)      // 74 cols
#define WR (TY + 2 * HALO)      // 58 rows

typedef _Float16 half2_t __attribute__((ext_vector_type(2)));

__device__ __forceinline__ float frcp(float x) { return __builtin_amdgcn_rcpf(x); }
__device__ __forceinline__ float ftanh(float x) {
    float t = __expf(x * 2.0f);
    return 1.0f - 2.0f * frcp(t + 1.0f);
}
__device__ __forceinline__ float fsigmoid(float x) {
    return frcp(1.0f + __expf(-x));
}
__device__ __forceinline__ half2_t splat(float v) {
    _Float16 h = (_Float16)v;
    half2_t r = {h, h};
    return r;
}

// ---- Pass 1: x1,x2 [B,64,H,W] f32 -> xt [B*16gg][H*W][8ch] fp16 (16 B/sample) ----
__global__ __launch_bounds__(256)
void transpose_x(const float* __restrict__ x1, const float* __restrict__ x2,
                 uint4* __restrict__ xt)
{
    const int pix = blockIdx.x * 256 + threadIdx.x;
    const int bg  = blockIdx.y;                        // b*16+gg
    const int b = bg >> 4, gg = bg & 15;
    const int s = gg >> 3, g = gg & 7;
    const float* xb = (s ? x2 : x1) + (size_t)(b * 64 + g * 8) * HW + pix;
    unsigned w0[4];
#pragma unroll
    for (int j = 0; j < 4; ++j) {
        half2_t h = {(_Float16)xb[(size_t)(2 * j) * HW],
                     (_Float16)xb[(size_t)(2 * j + 1) * HW]};
        w0[j] = __builtin_bit_cast(unsigned, h);
    }
    xt[(size_t)bg * HW + pix] = make_uint4(w0[0], w0[1], w0[2], w0[3]);
}

// ---- Pass 2: LDS-staged gather + modulated deformable conv, fp16 math ----
// Block = 512 threads = 32x16 pixel tile. Window [WR][WC] of uint4 staged in LDS.
__global__ __launch_bounds__(512, 4)
void dcn_lds(const float* __restrict__ off1, const float* __restrict__ flow1,
             const float* __restrict__ off2, const float* __restrict__ flow2,
             const float* __restrict__ wgt, const float* __restrict__ bias,
             const uint4* __restrict__ xt, float* __restrict__ out)
{
    __shared__ uint4 win[WR * WC];          // 67.1 KB
    __shared__ half2_t wsh2[9][4][4];       // 576 B

    // XCD chunk swizzle: 72 tiles = 8 XCDs * 9 contiguous tiles
    const int t_raw = blockIdx.x;
    const int tile  = (t_raw & 7) * 9 + (t_raw >> 3);
    const int gg = blockIdx.y;
    const int b  = blockIdx.z;
    const int tilex = tile % 6, tiley = tile / 6;
    const int X0 = tilex * TX, Y0 = tiley * TY;
    const int tid = threadIdx.x;
    const int lx = tid & 31, ly = tid >> 5;
    const int x = X0 + lx, y = Y0 + ly;
    const int pix = y * W + x;

    const uint4* tb = xt + (size_t)(b * 16 + gg) * HW;
    const int wy0 = Y0 - HALO, wx0 = X0 - HALO;

    // Stage window (zero-fill out-of-image so weight-0 reads stay finite)
    for (int i = tid; i < WR * WC; i += 512) {
        const int r = i / WC, c = i - r * WC;
        const int gy = wy0 + r, gx = wx0 + c;
        uint4 v = make_uint4(0, 0, 0, 0);
        if ((unsigned)gy < (unsigned)H && (unsigned)gx < (unsigned)W)
            v = tb[gy * W + gx];
        win[i] = v;
    }
    if (tid < 144) {
        const int k = tid >> 4, r = tid & 15, j = r >> 2, o = r & 3;
        const float lo = wgt[gg * 288 + o * 72 + (2 * j) * 9 + k];
        const float hi = wgt[gg * 288 + o * 72 + (2 * j + 1) * 9 + k];
        wsh2[k][j][o] = half2_t{(_Float16)lo, (_Float16)hi};
    }
    __syncthreads();

    const int s = gg >> 3;
    const int g = gg & 7;
    const float* ob = (s ? off2 : off1) + (size_t)b * 216 * HW + pix;
    const float* fb = (s ? flow2 : flow1) + (size_t)b * 2 * HW + pix;

    float rdy[9], rdx[9], rm[9];
#pragma unroll
    for (int k = 0; k < 9; ++k) {
        const int t = g * 9 + k;
        rdy[k] = ob[(size_t)(2 * t) * HW];
        rdx[k] = ob[(size_t)(2 * t + 1) * HW];
        rm[k]  = ob[(size_t)(144 + t) * HW];
    }
    const float f0 = fb[0];        // -> dx
    const float f1 = fb[HW];       // -> dy

    int     l00a[9];               // window-relative linear idx of corner 00 (valid when !fb)
    int     lyx[9];                // packed unclamped (ly0,lx0) for fallback
    int     fbm = 0;               // per-lane fallback mask
    half2_t hw00[9], hw01[9], hw10[9], hw11[9];
#pragma unroll
    for (int k = 0; k < 9; ++k) {
        const float mk = fsigmoid(rm[k]);
        const float py = ftanh(rdy[k]) * 10.0f + f1 + (float)(k / 3 + y - 1);
        const float px = ftanh(rdx[k]) * 10.0f + f0 + (float)(k % 3 + x - 1);
        const float fy0 = floorf(py);
        const float fx0 = floorf(px);
        const float wy = py - fy0;
        const float wx = px - fx0;
        const int y0 = (int)fy0, x0 = (int)fx0;
        const bool vy0 = (unsigned)y0       < (unsigned)H;
        const bool vy1 = (unsigned)(y0 + 1) < (unsigned)H;
        const bool vx0 = (unsigned)x0       < (unsigned)W;
        const bool vx1 = (unsigned)(x0 + 1) < (unsigned)W;
        const float w00 = (vy0 && vx0) ? (1.0f - wy) * (1.0f - wx) * mk : 0.0f;
        const float w01 = (vy0 && vx1) ? (1.0f - wy) * wx * mk : 0.0f;
        const float w10 = (vy1 && vx0) ? wy * (1.0f - wx) * mk : 0.0f;
        const float w11 = (vy1 && vx1) ? wy * wx * mk : 0.0f;
        hw00[k] = splat(w00);
        hw01[k] = splat(w01);
        hw10[k] = splat(w10);
        hw11[k] = splat(w11);

        const int ly0 = y0 - wy0;          // window-relative
        const int lx0 = x0 - wx0;
        const bool okwin = ((unsigned)ly0 <= (unsigned)(WR - 2)) &&
                           ((unsigned)lx0 <= (unsigned)(WC - 2));
        const bool anyw = (w00 + w01 + w10 + w11) > 0.0f;
        const bool needfb = (!okwin) && anyw;
        fbm |= needfb ? (1 << k) : 0;
        l00a[k] = okwin ? (ly0 * WC + lx0) : 0;
        lyx[k] = (lx0 & 0xffff) | (ly0 << 16);
    }

    float acc0 = bias[gg * 4 + 0];
    float acc1 = bias[gg * 4 + 1];
    float acc2 = bias[gg * 4 + 2];
    float acc3 = bias[gg * 4 + 3];

#pragma unroll
    for (int k = 0; k < 9; ++k) {
        const int base = l00a[k];
        uint4 q00 = win[base];
        uint4 q01 = win[base + 1];
        uint4 q10 = win[base + WC];
        uint4 q11 = win[base + WC + 1];
        if ((fbm >> k) & 1) {               // rare: sample outside staged window
            const int lx0v = (int)(short)(lyx[k] & 0xffff);
            const int ly0v = (int)(short)((unsigned)lyx[k] >> 16);
            const int ay0 = wy0 + ly0v, ax0 = wx0 + lx0v;
            const int iy0 = min(max(ay0, 0), H - 1);
            const int iy1 = min(max(ay0 + 1, 0), H - 1);
            const int ix0 = min(max(ax0, 0), W - 1);
            const int ix1 = min(max(ax0 + 1, 0), W - 1);
            q00 = tb[iy0 * W + ix0];
            q01 = tb[iy0 * W + ix1];
            q10 = tb[iy1 * W + ix0];
            q11 = tb[iy1 * W + ix1];
        }
        const half2_t* A  = (const half2_t*)&q00;
        const half2_t* Bq = (const half2_t*)&q01;
        const half2_t* Cq = (const half2_t*)&q10;
        const half2_t* Dq = (const half2_t*)&q11;
#pragma unroll
        for (int j = 0; j < 4; ++j) {
            half2_t vb = hw00[k] * A[j];
            vb = hw01[k] * Bq[j] + vb;
            vb = hw10[k] * Cq[j] + vb;
            vb = hw11[k] * Dq[j] + vb;
            half2_t w0 = wsh2[k][j][0];
            half2_t w1 = wsh2[k][j][1];
            half2_t w2 = wsh2[k][j][2];
            half2_t w3 = wsh2[k][j][3];
            acc0 = __builtin_amdgcn_fdot2(vb, w0, acc0, false);
            acc1 = __builtin_amdgcn_fdot2(vb, w1, acc1, false);
            acc2 = __builtin_amdgcn_fdot2(vb, w2, acc2, false);
            acc3 = __builtin_amdgcn_fdot2(vb, w3, acc3, false);
        }
    }

    float* op = out + ((size_t)(b * 64 + gg * 4)) * HW + pix;
    op[0 * HW] = acc0;
    op[1 * HW] = acc1;
    op[2 * HW] = acc2;
    op[3 * HW] = acc3;
}

// ---- Fallback (fp32 direct, known-correct) if ws too small ----
__global__ __launch_bounds__(256)
void dcn_fused(const float* __restrict__ x1, const float* __restrict__ off1,
               const float* __restrict__ flow1, const float* __restrict__ x2,
               const float* __restrict__ off2, const float* __restrict__ flow2,
               const float* __restrict__ wgt, const float* __restrict__ bias,
               float* __restrict__ out)
{
    const int tile = blockIdx.x;
    const int gg   = blockIdx.y;
    const int b    = blockIdx.z;
    const int tilex = tile % 6, tiley = tile / 6;
    const int lx = threadIdx.x & 31, ly = threadIdx.x >> 5;
    const int x = tilex * 32 + lx;
    const int y = tiley * 8 + ly;
    const int pix = y * W + x;

    __shared__ float wsh[9][8][4];
    for (int i = threadIdx.x; i < 288; i += 256) {
        int o = i / 72;
        int r = i - o * 72;
        int c = r / 9;
        int k = r - c * 9;
        wsh[k][c][o] = wgt[gg * 288 + i];
    }
    __syncthreads();

    const int s = gg >> 3;
    const int g = gg & 7;
    const float* xb = (s ? x2 : x1) + (size_t)(b * 64 + g * 8) * HW;
    const float* ob = (s ? off2 : off1) + (size_t)b * 216 * HW;
    const float* fb = (s ? flow2 : flow1) + (size_t)b * 2 * HW;

    const float f0 = fb[pix];
    const float f1 = fb[HW + pix];

    float acc0 = bias[gg * 4 + 0];
    float acc1 = bias[gg * 4 + 1];
    float acc2 = bias[gg * 4 + 2];
    float acc3 = bias[gg * 4 + 3];

    for (int k = 0; k < 9; ++k) {
        const int t = g * 9 + k;
        const float rdy = ob[(size_t)(2 * t) * HW + pix];
        const float rdx = ob[(size_t)(2 * t + 1) * HW + pix];
        const float rm  = ob[(size_t)(144 + t) * HW + pix];
        const float mk = fsigmoid(rm);
        const float py = ftanh(rdy) * 10.0f + f1 + (float)(k / 3 + y - 1);
        const float px = ftanh(rdx) * 10.0f + f0 + (float)(k % 3 + x - 1);
        const float fy0 = floorf(py);
        const float fx0 = floorf(px);
        const float wy = py - fy0;
        const float wx = px - fx0;
        const int y0 = (int)fy0, x0 = (int)fx0;
        const int y1 = y0 + 1, x1i = x0 + 1;
        const bool vy0 = (unsigned)y0  < (unsigned)H;
        const bool vy1 = (unsigned)y1  < (unsigned)H;
        const bool vx0 = (unsigned)x0  < (unsigned)W;
        const bool vx1 = (unsigned)x1i < (unsigned)W;
        float w00 = (1.0f - wy) * (1.0f - wx) * mk;
        float w01 = (1.0f - wy) * wx * mk;
        float w10 = wy * (1.0f - wx) * mk;
        float w11 = wy * wx * mk;
        w00 = (vy0 && vx0) ? w00 : 0.0f;
        w01 = (vy0 && vx1) ? w01 : 0.0f;
        w10 = (vy1 && vx0) ? w10 : 0.0f;
        w11 = (vy1 && vx1) ? w11 : 0.0f;
        const int iy0 = min(max(y0, 0), H - 1);
        const int iy1 = min(max(y1, 0), H - 1);
        const int ix0 = min(max(x0, 0), W - 1);
        const int ix1 = min(max(x1i, 0), W - 1);
        const int o00 = iy0 * W + ix0;
        const int o01 = iy0 * W + ix1;
        const int o10 = iy1 * W + ix0;
        const int o11 = iy1 * W + ix1;
#pragma unroll
        for (int c = 0; c < 8; ++c) {
            const float* p = xb + (size_t)c * HW;
            const float v = p[o00] * w00 + p[o01] * w01 + p[o10] * w10 + p[o11] * w11;
            acc0 = fmaf(wsh[k][c][0], v, acc0);
            acc1 = fmaf(wsh[k][c][1], v, acc1);
            acc2 = fmaf(wsh[k][c][2], v, acc2);
            acc3 = fmaf(wsh[k][c][3], v, acc3);
        }
    }

    float* op = out + ((size_t)(b * 64 + gg * 4)) * HW + pix;
    op[0 * HW] = acc0;
    op[1 * HW] = acc1;
    op[2 * HW] = acc2;
    op[3 * HW] = acc3;
}

extern "C" void kernel_launch(void* const* d_in, const int* in_sizes, int n_in,
                              void* d_out, int out_size, void* d_ws, size_t ws_size,
                              hipStream_t stream) {
    const float* x1    = (const float*)d_in[0];
    const float* off1  = (const float*)d_in[1];
    const float* flow1 = (const float*)d_in[2];
    const float* x2    = (const float*)d_in[3];
    const float* off2  = (const float*)d_in[4];
    const float* flow2 = (const float*)d_in[5];
    const float* wgt   = (const float*)d_in[6];
    const float* bias  = (const float*)d_in[7];
    float* out = (float*)d_out;

    const size_t need = (size_t)4 * 16 * HW * 8 * 2;   // 37.75 MB fp16 workspace
    if (ws_size >= need) {
        uint4* xt = (uint4*)d_ws;
        transpose_x<<<dim3(HW / 256, 64, 1), 256, 0, stream>>>(x1, x2, xt);
        dcn_lds<<<dim3(72, 16, 4), 512, 0, stream>>>(off1, flow1, off2, flow2,
                                                     wgt, bias, xt, out);
    } else {
        dcn_fused<<<dim3(144, 16, 4), 256, 0, stream>>>(x1, off1, flow1, x2, off2,
                                                        flow2, wgt, bias, out);
    }
}

// Round 6
// 194.367 us; speedup vs baseline: 3.8225x; 3.8225x over previous
//
#include <hip/hip_runtime.h>

#define H 192
#define W 192
#define HW (192 * 192)

typedef _Float16 half2_t __attribute__((ext_vector_type(2)));

__device__ __forceinline__ float frcp(float x) { return __builtin_amdgcn_rcpf(x); }
__device__ __forceinline__ float ftanh(float x) {
    float t = __expf(x * 2.0f);
    return 1.0f - 2.0f * frcp(t + 1.0f);
}
__device__ __forceinline__ float fsigmoid(float x) {
    return frcp(1.0f + __expf(-x));
}
__device__ __forceinline__ half2_t splat(float v) {
    _Float16 h = (_Float16)v;
    half2_t r = {h, h};
    return r;
}

// ---- Pass 1: x1,x2 [B,64,H,W] f32 -> xt [B*16gg][H*W][8ch] fp16 (16 B/sample) ----
__global__ __launch_bounds__(256)
void transpose_x(const float* __restrict__ x1, const float* __restrict__ x2,
                 uint4* __restrict__ xt)
{
    const int pix = blockIdx.x * 256 + threadIdx.x;
    const int bg  = blockIdx.y;                        // b*16+gg
    const int b = bg >> 4, gg = bg & 15;
    const int s = gg >> 3, g = gg & 7;
    const float* xb = (s ? x2 : x1) + (size_t)(b * 64 + g * 8) * HW + pix;
    unsigned w0[4];
#pragma unroll
    for (int j = 0; j < 4; ++j) {
        half2_t h = {(_Float16)xb[(size_t)(2 * j) * HW],
                     (_Float16)xb[(size_t)(2 * j + 1) * HW]};
        w0[j] = __builtin_bit_cast(unsigned, h);
    }
    xt[(size_t)bg * HW + pix] = make_uint4(w0[0], w0[1], w0[2], w0[3]);
}

// ---- Pass 2: fused offset-prep + modulated deformable conv, fp16 math ----
// Exact R2 structure (52 VGPR, no spill) + chunked XCD swizzle.
__global__ __launch_bounds__(256)
void dcn_gather(const float* __restrict__ off1, const float* __restrict__ flow1,
                const float* __restrict__ off2, const float* __restrict__ flow2,
                const float* __restrict__ wgt, const float* __restrict__ bias,
                const uint4* __restrict__ xt, float* __restrict__ out)
{
    // Chunked XCD swizzle: 144 tiles = 8 XCDs * 18 contiguous tiles.
    // Default map gives XCD = bid%8 (scattered); remap so each XCD owns
    // 3 contiguous tile-rows (192x48 px ~ 9 MB working set incl. halo).
    const int t_raw = blockIdx.x;
    const int tile  = (t_raw & 7) * 18 + (t_raw >> 3);
    const int gg   = blockIdx.y;
    const int b    = blockIdx.z;
    const int tilex = tile % 6, tiley = tile / 6;
    const int lx = threadIdx.x & 31, ly = threadIdx.x >> 5;
    const int x = tilex * 32 + lx;
    const int y = tiley * 8 + ly;
    const int pix = y * W + x;

    // weights as half2 channel-pairs: wsh2[k][j][o]
    __shared__ half2_t wsh2[9][4][4];
    for (int i = threadIdx.x; i < 144; i += 256) {
        const int k = i >> 4, r = i & 15, j = r >> 2, o = r & 3;
        const float lo = wgt[gg * 288 + o * 72 + (2 * j) * 9 + k];
        const float hi = wgt[gg * 288 + o * 72 + (2 * j + 1) * 9 + k];
        wsh2[k][j][o] = half2_t{(_Float16)lo, (_Float16)hi};
    }
    __syncthreads();

    const int s = gg >> 3;
    const int g = gg & 7;
    const float* ob = (s ? off2 : off1) + (size_t)b * 216 * HW + pix;
    const float* fb = (s ? flow2 : flow1) + (size_t)b * 2 * HW + pix;
    const uint4* tb = xt + (size_t)(b * 16 + gg) * HW;

    float rdy[9], rdx[9], rm[9];
#pragma unroll
    for (int k = 0; k < 9; ++k) {
        const int t = g * 9 + k;
        rdy[k] = ob[(size_t)(2 * t) * HW];
        rdx[k] = ob[(size_t)(2 * t + 1) * HW];
        rm[k]  = ob[(size_t)(144 + t) * HW];
    }
    const float f0 = fb[0];        // -> dx
    const float f1 = fb[HW];       // -> dy

    int     idc[9][4];
    half2_t hw00[9], hw01[9], hw10[9], hw11[9];
#pragma unroll
    for (int k = 0; k < 9; ++k) {
        const float mk = fsigmoid(rm[k]);
        const float py = ftanh(rdy[k]) * 10.0f + f1 + (float)(k / 3 + y - 1);
        const float px = ftanh(rdx[k]) * 10.0f + f0 + (float)(k % 3 + x - 1);
        const float fy0 = floorf(py);
        const float fx0 = floorf(px);
        const float wy = py - fy0;
        const float wx = px - fx0;
        const int y0 = (int)fy0, x0 = (int)fx0;
        const int y1 = y0 + 1, x1i = x0 + 1;
        const bool vy0 = (unsigned)y0  < (unsigned)H;
        const bool vy1 = (unsigned)y1  < (unsigned)H;
        const bool vx0 = (unsigned)x0  < (unsigned)W;
        const bool vx1 = (unsigned)x1i < (unsigned)W;
        float w00 = (1.0f - wy) * (1.0f - wx) * mk;
        float w01 = (1.0f - wy) * wx * mk;
        float w10 = wy * (1.0f - wx) * mk;
        float w11 = wy * wx * mk;
        hw00[k] = splat((vy0 && vx0) ? w00 : 0.0f);
        hw01[k] = splat((vy0 && vx1) ? w01 : 0.0f);
        hw10[k] = splat((vy1 && vx0) ? w10 : 0.0f);
        hw11[k] = splat((vy1 && vx1) ? w11 : 0.0f);
        const int iy0 = min(max(y0, 0), H - 1);
        const int iy1 = min(max(y1, 0), H - 1);
        const int ix0 = min(max(x0, 0), W - 1);
        const int ix1 = min(max(x1i, 0), W - 1);
        idc[k][0] = iy0 * W + ix0;
        idc[k][1] = iy0 * W + ix1;
        idc[k][2] = iy1 * W + ix0;
        idc[k][3] = iy1 * W + ix1;
    }

    float acc0 = bias[gg * 4 + 0];
    float acc1 = bias[gg * 4 + 1];
    float acc2 = bias[gg * 4 + 2];
    float acc3 = bias[gg * 4 + 3];

#pragma unroll
    for (int k = 0; k < 9; ++k) {
        const uint4 q00 = tb[idc[k][0]];
        const uint4 q01 = tb[idc[k][1]];
        const uint4 q10 = tb[idc[k][2]];
        const uint4 q11 = tb[idc[k][3]];
        const half2_t* A = (const half2_t*)&q00;
        const half2_t* Bq = (const half2_t*)&q01;
        const half2_t* Cq = (const half2_t*)&q10;
        const half2_t* Dq = (const half2_t*)&q11;
#pragma unroll
        for (int j = 0; j < 4; ++j) {
            half2_t vb = hw00[k] * A[j];
            vb = hw01[k] * Bq[j] + vb;
            vb = hw10[k] * Cq[j] + vb;
            vb = hw11[k] * Dq[j] + vb;
            half2_t w0 = wsh2[k][j][0];
            half2_t w1 = wsh2[k][j][1];
            half2_t w2 = wsh2[k][j][2];
            half2_t w3 = wsh2[k][j][3];
            acc0 = __builtin_amdgcn_fdot2(vb, w0, acc0, false);
            acc1 = __builtin_amdgcn_fdot2(vb, w1, acc1, false);
            acc2 = __builtin_amdgcn_fdot2(vb, w2, acc2, false);
            acc3 = __builtin_amdgcn_fdot2(vb, w3, acc3, false);
        }
    }

    float* op = out + ((size_t)(b * 64 + gg * 4)) * HW + pix;
    op[0 * HW] = acc0;
    op[1 * HW] = acc1;
    op[2 * HW] = acc2;
    op[3 * HW] = acc3;
}

// ---- Fallback (fp32 direct, known-correct) if ws too small ----
__global__ __launch_bounds__(256)
void dcn_fused(const float* __restrict__ x1, const float* __restrict__ off1,
               const float* __restrict__ flow1, const float* __restrict__ x2,
               const float* __restrict__ off2, const float* __restrict__ flow2,
               const float* __restrict__ wgt, const float* __restrict__ bias,
               float* __restrict__ out)
{
    const int tile = blockIdx.x;
    const int gg   = blockIdx.y;
    const int b    = blockIdx.z;
    const int tilex = tile % 6, tiley = tile / 6;
    const int lx = threadIdx.x & 31, ly = threadIdx.x >> 5;
    const int x = tilex * 32 + lx;
    const int y = tiley * 8 + ly;
    const int pix = y * W + x;

    __shared__ float wsh[9][8][4];
    for (int i = threadIdx.x; i < 288; i += 256) {
        int o = i / 72;
        int r = i - o * 72;
        int c = r / 9;
        int k = r - c * 9;
        wsh[k][c][o] = wgt[gg * 288 + i];
    }
    __syncthreads();

    const int s = gg >> 3;
    const int g = gg & 7;
    const float* xb = (s ? x2 : x1) + (size_t)(b * 64 + g * 8) * HW;
    const float* ob = (s ? off2 : off1) + (size_t)b * 216 * HW;
    const float* fb = (s ? flow2 : flow1) + (size_t)b * 2 * HW;

    const float f0 = fb[pix];
    const float f1 = fb[HW + pix];

    float acc0 = bias[gg * 4 + 0];
    float acc1 = bias[gg * 4 + 1];
    float acc2 = bias[gg * 4 + 2];
    float acc3 = bias[gg * 4 + 3];

    for (int k = 0; k < 9; ++k) {
        const int t = g * 9 + k;
        const float rdy = ob[(size_t)(2 * t) * HW + pix];
        const float rdx = ob[(size_t)(2 * t + 1) * HW + pix];
        const float rm  = ob[(size_t)(144 + t) * HW + pix];
        const float mk = fsigmoid(rm);
        const float py = ftanh(rdy) * 10.0f + f1 + (float)(k / 3 + y - 1);
        const float px = ftanh(rdx) * 10.0f + f0 + (float)(k % 3 + x - 1);
        const float fy0 = floorf(py);
        const float fx0 = floorf(px);
        const float wy = py - fy0;
        const float wx = px - fx0;
        const int y0 = (int)fy0, x0 = (int)fx0;
        const int y1 = y0 + 1, x1i = x0 + 1;
        const bool vy0 = (unsigned)y0  < (unsigned)H;
        const bool vy1 = (unsigned)y1  < (unsigned)H;
        const bool vx0 = (unsigned)x0  < (unsigned)W;
        const bool vx1 = (unsigned)x1i < (unsigned)W;
        float w00 = (1.0f - wy) * (1.0f - wx) * mk;
        float w01 = (1.0f - wy) * wx * mk;
        float w10 = wy * (1.0f - wx) * mk;
        float w11 = wy * wx * mk;
        w00 = (vy0 && vx0) ? w00 : 0.0f;
        w01 = (vy0 && vx1) ? w01 : 0.0f;
        w10 = (vy1 && vx0) ? w10 : 0.0f;
        w11 = (vy1 && vx1) ? w11 : 0.0f;
        const int iy0 = min(max(y0, 0), H - 1);
        const int iy1 = min(max(y1, 0), H - 1);
        const int ix0 = min(max(x0, 0), W - 1);
        const int ix1 = min(max(x1i, 0), W - 1);
        const int o00 = iy0 * W + ix0;
        const int o01 = iy0 * W + ix1;
        const int o10 = iy1 * W + ix0;
        const int o11 = iy1 * W + ix1;
#pragma unroll
        for (int c = 0; c < 8; ++c) {
            const float* p = xb + (size_t)c * HW;
            const float v = p[o00] * w00 + p[o01] * w01 + p[o10] * w10 + p[o11] * w11;
            acc0 = fmaf(wsh[k][c][0], v, acc0);
            acc1 = fmaf(wsh[k][c][1], v, acc1);
            acc2 = fmaf(wsh[k][c][2], v, acc2);
            acc3 = fmaf(wsh[k][c][3], v, acc3);
        }
    }

    float* op = out + ((size_t)(b * 64 + gg * 4)) * HW + pix;
    op[0 * HW] = acc0;
    op[1 * HW] = acc1;
    op[2 * HW] = acc2;
    op[3 * HW] = acc3;
}

extern "C" void kernel_launch(void* const* d_in, const int* in_sizes, int n_in,
                              void* d_out, int out_size, void* d_ws, size_t ws_size,
                              hipStream_t stream) {
    const float* x1    = (const float*)d_in[0];
    const float* off1  = (const float*)d_in[1];
    const float* flow1 = (const float*)d_in[2];
    const float* x2    = (const float*)d_in[3];
    const float* off2  = (const float*)d_in[4];
    const float* flow2 = (const float*)d_in[5];
    const float* wgt   = (const float*)d_in[6];
    const float* bias  = (const float*)d_in[7];
    float* out = (float*)d_out;

    const size_t need = (size_t)4 * 16 * HW * 8 * 2;   // 37.75 MB fp16 workspace
    if (ws_size >= need) {
        uint4* xt = (uint4*)d_ws;
        transpose_x<<<dim3(HW / 256, 64, 1), 256, 0, stream>>>(x1, x2, xt);
        dcn_gather<<<dim3(144, 16, 4), 256, 0, stream>>>(off1, flow1, off2, flow2,
                                                         wgt, bias, xt, out);
    } else {
        dcn_fused<<<dim3(144, 16, 4), 256, 0, stream>>>(x1, off1, flow1, x2, off2,
                                                        flow2, wgt, bias, out);
    }
}